// Round 15
// baseline (181.273 us; speedup 1.0000x reference)
//
#include <hip/hip_runtime.h>

// MultiHeadAttention: N=8, C=256, L=2048, H=8, D=32. softmax scale = C^-0.5 = 1/16.
// Inputs fp32, output fp32. Internal bf16 MFMA, fp32 accumulate.
// R15: convert_weights dispatch ELIMINATED (qkv/out inline-convert fp32 weights,
// same RNE packing -> bit-identical). attn split-K combine done in TWO passes
// over a reused [3][64][21] LDS buffer: 28.6 -> 16.1 KB, LDS block limit
// 5 -> 10 blocks/CU. attn main loop frozen from R14 (zero-LDS, no prefetch).

typedef __bf16 bf8 __attribute__((ext_vector_type(8)));
typedef float f4 __attribute__((ext_vector_type(4)));
typedef float f32x4 __attribute__((ext_vector_type(4)));
typedef unsigned short u16;
typedef unsigned int u32;
typedef u16 u16x4 __attribute__((ext_vector_type(4)));
typedef u16 u16x8 __attribute__((ext_vector_type(8)));

__device__ __forceinline__ u16 f2bf(float f) {
  __bf16 h = (__bf16)f;                 // v_cvt (RNE)
  return __builtin_bit_cast(u16, h);
}
__device__ __forceinline__ u32 pk2bf(float a, float b) {  // low=a, high=b (RNE)
  return ((u32)f2bf(b) << 16) | (u32)f2bf(a);
}
// truncating pack: low16 = hi16(a), high16 = hi16(b); 1 v_perm_b32
__device__ __forceinline__ u32 pktrunc(float a, float b) {
  return __builtin_amdgcn_perm(__builtin_bit_cast(u32, b),
                               __builtin_bit_cast(u32, a), 0x07060302u);
}
__device__ __forceinline__ float exp2_fast(float x) {
  return __builtin_amdgcn_exp2f(x);     // v_exp_f32
}

#define MFMA(a, b, c) __builtin_amdgcn_mfma_f32_16x16x32_bf16((a), (b), (c), 0, 0, 0)

union bf8u { u32 u[4]; bf8 v; };
__device__ __forceinline__ bf8 mkbf8(u32 a, u32 b, u32 c, u32 d) {
  bf8u t; t.u[0] = a; t.u[1] = b; t.u[2] = c; t.u[3] = d; return t.v;
}
// load 8 consecutive fp32 -> bf8 fragment (RNE, same as convert kernel did)
__device__ __forceinline__ bf8 ldw8(const float* p) {
  f32x4 u = *(const f32x4*)p;
  f32x4 v = *(const f32x4*)(p + 4);
  return mkbf8(pk2bf(u[0], u[1]), pk2bf(u[2], u[3]),
               pk2bf(v[0], v[1]), pk2bf(v[2], v[3]));
}

// ---------------------------------------------------------------------------
// Kernel 1: Q/K/V projections, double-buffered x staging (fp32 in), weights
// converted inline from fp32. qbuf [n][h][l][d] PRE-SCALED by log2e/16;
// kbuf [n][h][l][d] (packed 8B stores). V computed operand-swapped (C[l][o])
// -> vbuf [n][c][2048] in the A-frag l-permuted layout (pos p=quad*8+j holds
// l = 32g + (j<4 ? 4*quad+j : 16+4*quad+j-4)), two 16B stores per lane.
__global__ __launch_bounds__(256) void qkv_proj(
    const float* __restrict__ x, const float* __restrict__ Wq,
    const float* __restrict__ Wk, const float* __restrict__ Wv,
    u16* __restrict__ qbuf, u16* __restrict__ kbuf, u16* __restrict__ vbuf) {
  __shared__ __align__(16) u16 xt[2][64 * 40];   // x^T tile [64 l][32 c], pad 40
  const int n = blockIdx.z;
  const int o0 = blockIdx.y * 64;
  const int l0 = blockIdx.x * 64;
  const int tid = threadIdx.x;
  const int w = tid >> 6, lane = tid & 63, quad = lane >> 4, l16 = lane & 15;
  const int ow = o0 + w * 16;
  const float SC = 0.09019327066650391f;   // log2(e)/16

  f4 accq[4], acck[4], accv[4];
#pragma unroll
  for (int lt = 0; lt < 4; ++lt) {
    accq[lt] = (f4){0.f, 0.f, 0.f, 0.f};
    acck[lt] = (f4){0.f, 0.f, 0.f, 0.f};
    accv[lt] = (f4){0.f, 0.f, 0.f, 0.f};
  }

  const int cp = tid >> 4;            // c-pair 0..15 -> c = 2cp, 2cp+1
  const int lq = (tid & 15) * 4;      // 4 l's

  auto stage = [&](int c0, int buf) {
    const float* xp = x + (n * 256 + c0 + 2 * cp) * 2048 + l0 + lq;
    f32x4 r0 = *(const f32x4*)xp;
    f32x4 r1 = *(const f32x4*)(xp + 2048);
#pragma unroll
    for (int i = 0; i < 4; ++i)
      *(u32*)&xt[buf][(lq + i) * 40 + 2 * cp] = pk2bf(r0[i], r1[i]);
  };

  const float* wqp = Wq + (ow + l16) * 256 + quad * 8;
  const float* wkp = Wk + (ow + l16) * 256 + quad * 8;
  const float* wvp = Wv + (ow + l16) * 256 + quad * 8;

  stage(0, 0);
  for (int s = 0; s < 8; ++s) {
    __syncthreads();
    if (s < 7) stage((s + 1) * 32, (s + 1) & 1);
    const int c0 = s * 32;
    bf8 a0 = ldw8(wqp + c0);
    bf8 a1 = ldw8(wkp + c0);
    bf8 a2 = ldw8(wvp + c0);
    const u16* xb = xt[s & 1];
#pragma unroll
    for (int lt = 0; lt < 4; ++lt) {
      bf8 b = *(const bf8*)&xb[(lt * 16 + l16) * 40 + quad * 8];
      accq[lt] = MFMA(a0, b, accq[lt]);
      acck[lt] = MFMA(a1, b, acck[lt]);
      accv[lt] = MFMA(b, a2, accv[lt]);   // swapped: C[l][o], o = ow + l16
    }
  }

  // ---- epilogue ----
  const int hh = ow >> 5;                        // head index (const over r)
  const int dbase = (ow & 31) + quad * 4;        // d offset, 8B aligned
#pragma unroll
  for (int lt = 0; lt < 4; ++lt) {
    const int l = l0 + lt * 16 + l16;
    const size_t base = ((size_t)(n * 8 + hh) * 2048 + l) * 32 + dbase;
    u16x4 qv, kv;
#pragma unroll
    for (int r = 0; r < 4; ++r) {
      qv[r] = f2bf(accq[lt][r] * SC);
      kv[r] = f2bf(acck[lt][r]);
    }
    *(u16x4*)(qbuf + base) = qv;
    *(u16x4*)(kbuf + base) = kv;
  }
  // V: lane holds l = 32g+4quad+r (tile 2g) and 32g+16+4quad+r (tile 2g+1),
  // d-col o = ow + l16 -> exactly the permuted-A-frag 16B run.
#pragma unroll
  for (int g = 0; g < 2; ++g) {
    u16x8 vv;
#pragma unroll
    for (int r = 0; r < 4; ++r) {
      vv[r] = f2bf(accv[2 * g][r]);
      vv[4 + r] = f2bf(accv[2 * g + 1][r]);
    }
    *(u16x8*)(vbuf + ((size_t)(n * 256 + ow + l16)) * 2048 + l0 + g * 32 + quad * 8) = vv;
  }
}

// ---------------------------------------------------------------------------
// Kernel 2: attention, 4 waves/block, split-K: wave w covers k in
// [512w,512w+512) for the same 64 q. Zero-LDS main loop (S^T = K*Q^T,
// lane-local exp2 + pktrunc -> PV B-frags, permuted-V 16B A-frags, no
// explicit prefetch). Split-K combine in TWO passes over a reused
// [3][64][21] LDS buffer (16.1 KB; stride 21 coprime 32 -> conflict-free).
// Grid (64 head, 32 qblk): linear = head + 64*qblk -> head h on XCD h%8.
__global__ __launch_bounds__(256) void attn(
    const u16* __restrict__ qbuf, const u16* __restrict__ kbuf,
    const u16* __restrict__ vbuf, u16* __restrict__ abuf) {
  __shared__ float Osh[3][64][21];              // reused across 2 passes
  const int head = blockIdx.x, qblk = blockIdx.y;
  const int n = head >> 3, h = head & 7;
  const int tid = threadIdx.x;
  const int w = tid >> 6, lane = tid & 63;
  const int quad = lane >> 4, l16 = lane & 15;
  const int q0 = qblk * 64;
  const int kc0 = w * 512;

  const u16* kb = kbuf + (size_t)head * 2048 * 32 + l16 * 32 + quad * 8;
  const u16* vb = vbuf + ((size_t)n * 256 + h * 32 + l16) * 2048 + quad * 8;

  bf8 aq[4];                                    // Q B-op frags (16x16x32)
#pragma unroll
  for (int qt = 0; qt < 4; ++qt)
    aq[qt] = *(const bf8*)(qbuf + ((size_t)head * 2048 + q0 + qt * 16 + l16) * 32 + quad * 8);

  f4 O[2][4];                                   // O^T accum [dt][qt]
  float lsum[4];
#pragma unroll
  for (int qt = 0; qt < 4; ++qt) {
    O[0][qt] = (f4){0.f, 0.f, 0.f, 0.f};
    O[1][qt] = (f4){0.f, 0.f, 0.f, 0.f};
    lsum[qt] = 0.f;
  }

  for (int kc = kc0; kc < kc0 + 512; kc += 64) {
    bf8 bk[4], vf[4];
#pragma unroll
    for (int kt = 0; kt < 4; ++kt) bk[kt] = *(const bf8*)(kb + (kc + kt * 16) * 32);
#pragma unroll
    for (int dt = 0; dt < 2; ++dt)
#pragma unroll
      for (int g = 0; g < 2; ++g)
        vf[dt * 2 + g] = *(const bf8*)(vb + dt * 16 * 2048 + kc + g * 32);

#pragma unroll
    for (int qt = 0; qt < 4; ++qt) {
      f4 z = (f4){0.f, 0.f, 0.f, 0.f};
      f4 s0 = MFMA(bk[0], aq[qt], z);           // S^T tiles (A=K, B=Q)
      f4 s1 = MFMA(bk[1], aq[qt], z);
      f4 s2 = MFMA(bk[2], aq[qt], z);
      f4 s3 = MFMA(bk[3], aq[qt], z);
      f4 e0, e1, e2, e3;
#pragma unroll
      for (int r = 0; r < 4; ++r) {
        e0[r] = exp2_fast(s0[r]);               // scale pre-folded into qbuf
        e1[r] = exp2_fast(s1[r]);
        e2[r] = exp2_fast(s2[r]);
        e3[r] = exp2_fast(s3[r]);
      }
      f4 t01 = e0 + e1, t23 = e2 + e3;
      f4 t = t01 + t23;
      lsum[qt] += (t[0] + t[1]) + (t[2] + t[3]);
      // B-frags: group 0 = tiles 0,1; group 1 = tiles 2,3 (k-permuted pi)
      bf8 B0 = mkbf8(pktrunc(e0[0], e0[1]), pktrunc(e0[2], e0[3]),
                     pktrunc(e1[0], e1[1]), pktrunc(e1[2], e1[3]));
      bf8 B1 = mkbf8(pktrunc(e2[0], e2[1]), pktrunc(e2[2], e2[3]),
                     pktrunc(e3[0], e3[1]), pktrunc(e3[2], e3[3]));
#pragma unroll
      for (int dt = 0; dt < 2; ++dt) {
        f4 o = O[dt][qt];
        o = MFMA(vf[dt * 2 + 0], B0, o);        // A = permuted V (direct 16B)
        o = MFMA(vf[dt * 2 + 1], B1, o);
        O[dt][qt] = o;
      }
    }
  }

  // per-qt: reduce lsum across the 4 quads holding this q's k-slices
#pragma unroll
  for (int qt = 0; qt < 4; ++qt) {
    float s = lsum[qt];
    s += __shfl_xor(s, 16);
    s += __shfl_xor(s, 32);
    lsum[qt] = s;
  }

  // ---- split-K combine, pass 0: O[0] + lsum ----
  if (w > 0) {
#pragma unroll
    for (int qt = 0; qt < 4; ++qt) {
#pragma unroll
      for (int r = 0; r < 4; ++r)
        Osh[w - 1][lane][qt * 4 + r] = O[0][qt][r];
      Osh[w - 1][lane][16 + qt] = lsum[qt];
    }
  }
  __syncthreads();
  if (w == 0) {
#pragma unroll
    for (int p = 0; p < 3; ++p) {
#pragma unroll
      for (int qt = 0; qt < 4; ++qt) {
#pragma unroll
        for (int r = 0; r < 4; ++r)
          O[0][qt][r] += Osh[p][lane][qt * 4 + r];
        lsum[qt] += Osh[p][lane][16 + qt];
      }
    }
  }
  __syncthreads();
  // ---- pass 1: O[1] (buffer reused) ----
  if (w > 0) {
#pragma unroll
    for (int qt = 0; qt < 4; ++qt)
#pragma unroll
      for (int r = 0; r < 4; ++r)
        Osh[w - 1][lane][qt * 4 + r] = O[1][qt][r];
  }
  __syncthreads();
  if (w == 0) {
#pragma unroll
    for (int p = 0; p < 3; ++p)
#pragma unroll
      for (int qt = 0; qt < 4; ++qt)
#pragma unroll
        for (int r = 0; r < 4; ++r)
          O[1][qt][r] += Osh[p][lane][qt * 4 + r];

#pragma unroll
    for (int qt = 0; qt < 4; ++qt) {
      const float inv = 1.0f / lsum[qt];        // q = l16
      const int q = q0 + qt * 16 + l16;
#pragma unroll
      for (int dt = 0; dt < 2; ++dt) {
        u16x4 ov;
#pragma unroll
        for (int r = 0; r < 4; ++r) ov[r] = f2bf(O[dt][qt][r] * inv);
        *(u16x4*)(abuf + ((size_t)n * 2048 + q) * 256 + h * 32 + dt * 16 + quad * 4) = ov;
      }
    }
  }
}

// ---------------------------------------------------------------------------
// Kernel 3: out = Wo @ attn_out + bo (fp32 output).  attn_out stored [n][l][c]
// = B^T form -> 16B contiguous B-frag loads; prefetch-1 on raw fp32 W and B;
// Wo converted inline (RNE), bo read fp32.
__global__ __launch_bounds__(256) void out_proj(
    const u16* __restrict__ abuf, const float* __restrict__ Wo,
    const float* __restrict__ bo, float* __restrict__ out) {
  const int n = blockIdx.z;
  const int o0 = blockIdx.y * 64;
  const int l0 = blockIdx.x * 64;
  const int tid = threadIdx.x;
  const int w = tid >> 6, lane = tid & 63, quad = lane >> 4, l16 = lane & 15;
  const int ow = o0 + w * 16;

  const float* wp = Wo + (ow + l16) * 256 + quad * 8;
  const u16* ab = abuf + ((size_t)n * 2048 + l0 + l16) * 256 + quad * 8;

  f4 acc[4];
#pragma unroll
  for (int lt = 0; lt < 4; ++lt) acc[lt] = (f4){0.f, 0.f, 0.f, 0.f};

  f32x4 wa0 = *(const f32x4*)wp, wa1 = *(const f32x4*)(wp + 4);
  bf8 b[4];
#pragma unroll
  for (int lt = 0; lt < 4; ++lt) b[lt] = *(const bf8*)(ab + lt * 16 * 256);

  for (int c0 = 0; c0 < 256; c0 += 32) {
    const int cn = (c0 < 224) ? c0 + 32 : 0;
    f32x4 wn0 = *(const f32x4*)(wp + cn), wn1 = *(const f32x4*)(wp + cn + 4);
    bf8 nb[4];
#pragma unroll
    for (int lt = 0; lt < 4; ++lt)
      nb[lt] = *(const bf8*)(ab + lt * 16 * 256 + cn);
    bf8 a = mkbf8(pk2bf(wa0[0], wa0[1]), pk2bf(wa0[2], wa0[3]),
                  pk2bf(wa1[0], wa1[1]), pk2bf(wa1[2], wa1[3]));
#pragma unroll
    for (int lt = 0; lt < 4; ++lt) acc[lt] = MFMA(a, b[lt], acc[lt]);
    wa0 = wn0; wa1 = wn1;
#pragma unroll
    for (int lt = 0; lt < 4; ++lt) b[lt] = nb[lt];
  }
#pragma unroll
  for (int r = 0; r < 4; ++r) {
    const int o = ow + quad * 4 + r;
    const float bias = bo[o];
#pragma unroll
    for (int lt = 0; lt < 4; ++lt) {
      out[((size_t)n * 256 + o) * 2048 + l0 + lt * 16 + l16] = acc[lt][r] + bias;
    }
  }
}

// ---------------------------------------------------------------------------
extern "C" void kernel_launch(void* const* d_in, const int* in_sizes, int n_in,
                              void* d_out, int out_size, void* d_ws, size_t ws_size,
                              hipStream_t stream) {
  const float* x  = (const float*)d_in[0];
  const float* Wq = (const float*)d_in[1];
  const float* Wk = (const float*)d_in[2];
  const float* Wv = (const float*)d_in[3];
  const float* Wo = (const float*)d_in[4];
  const float* bo = (const float*)d_in[5];
  float* out = (float*)d_out;

  u16* ws = (u16*)d_ws;
  u16* qbuf = ws;                      // [8][8][2048][32] bf16 = 8 MB (pre-scaled)
  u16* kbuf = qbuf + 4194304;          // 8 MB
  u16* vbuf = kbuf + 4194304;          // [8][256][2048]   = 8 MB (A-frag permuted)
  u16* abuf = vbuf + 4194304;          // [8][2048][256]   = 8 MB

  qkv_proj<<<dim3(32, 4, 8), 256, 0, stream>>>(x, Wq, Wk, Wv,
                                               qbuf, kbuf, vbuf);
  attn<<<dim3(64, 32), 256, 0, stream>>>(qbuf, kbuf, vbuf, abuf);
  out_proj<<<dim3(32, 4, 8), 256, 0, stream>>>(abuf, Wo, bo, out);
}

// Round 16
// 172.324 us; speedup vs baseline: 1.0519x; 1.0519x over previous
//
#include <hip/hip_runtime.h>

// MultiHeadAttention: N=8, C=256, L=2048, H=8, D=32. softmax scale = C^-0.5 = 1/16.
// Inputs fp32, output fp32. Internal bf16 MFMA, fp32 accumulate.
// R16 = R14 (best, 166.3us) with qkv_proj rewritten BARRIER-FREE / LDS-FREE:
// x^T fragments loaded directly from global (8 coalesced dwords/lane, RNE
// pack in-register; 4x re-read absorbed by L3), bf16 weights from the convert
// dispatch (twice-confirmed better than inline conversion). Same fragment
// serves as B (Q,K) and A (swapped V). attn + out_proj frozen from R14.

typedef __bf16 bf8 __attribute__((ext_vector_type(8)));
typedef float f4 __attribute__((ext_vector_type(4)));
typedef float f32x4 __attribute__((ext_vector_type(4)));
typedef unsigned short u16;
typedef unsigned int u32;
typedef u16 u16x4 __attribute__((ext_vector_type(4)));
typedef u16 u16x8 __attribute__((ext_vector_type(8)));

__device__ __forceinline__ u16 f2bf(float f) {
  __bf16 h = (__bf16)f;                 // v_cvt (RNE)
  return __builtin_bit_cast(u16, h);
}
__device__ __forceinline__ float bf2f(u16 b) {
  union { u32 u; float f; } v; v.u = ((u32)b) << 16;
  return v.f;
}
__device__ __forceinline__ u32 pk2bf(float a, float b) {  // low=a, high=b (RNE)
  return ((u32)f2bf(b) << 16) | (u32)f2bf(a);
}
// truncating pack: low16 = hi16(a), high16 = hi16(b); 1 v_perm_b32
__device__ __forceinline__ u32 pktrunc(float a, float b) {
  return __builtin_amdgcn_perm(__builtin_bit_cast(u32, b),
                               __builtin_bit_cast(u32, a), 0x07060302u);
}
__device__ __forceinline__ float exp2_fast(float x) {
  return __builtin_amdgcn_exp2f(x);     // v_exp_f32
}

#define MFMA(a, b, c) __builtin_amdgcn_mfma_f32_16x16x32_bf16((a), (b), (c), 0, 0, 0)

union bf8u { u32 u[4]; bf8 v; };
__device__ __forceinline__ bf8 mkbf8(u32 a, u32 b, u32 c, u32 d) {
  bf8u t; t.u[0] = a; t.u[1] = b; t.u[2] = c; t.u[3] = d; return t.v;
}

// ---------------------------------------------------------------------------
// Kernel 0: convert Wq/Wk/Wv/Wo/bo fp32 -> bf16 ws copies.
__global__ __launch_bounds__(256) void convert_weights(
    const float* __restrict__ Wq, const float* __restrict__ Wk,
    const float* __restrict__ Wv, const float* __restrict__ Wo,
    const float* __restrict__ bo,
    u16* __restrict__ Wqb, u16* __restrict__ Wkb, u16* __restrict__ Wvb,
    u16* __restrict__ Wob, u16* __restrict__ bob) {
  const int tid = threadIdx.x;
  const int seg = blockIdx.x >> 6;
  const int blk = blockIdx.x & 63;
  const float* s; u16* d;
  if (seg == 0)      { s = Wq; d = Wqb; }
  else if (seg == 1) { s = Wk; d = Wkb; }
  else if (seg == 2) { s = Wv; d = Wvb; }
  else               { s = Wo; d = Wob; }
  const int base = blk * 1024 + tid * 4;
  f32x4 v = *(const f32x4*)(s + base);
  u16x4 o;
#pragma unroll
  for (int i = 0; i < 4; ++i) o[i] = f2bf(v[i]);
  *(u16x4*)(d + base) = o;
  if (blockIdx.x == 0 && tid < 64) {
    const int bb = tid * 4;
    f32x4 bv = *(const f32x4*)(bo + bb);
    u16x4 ob;
#pragma unroll
    for (int i = 0; i < 4; ++i) ob[i] = f2bf(bv[i]);
    *(u16x4*)(bob + bb) = ob;
  }
}

// ---------------------------------------------------------------------------
// Kernel 1: Q/K/V projections — BARRIER-FREE, LDS-FREE. Per K-step: 3 bf16
// W-frags (16B loads) + 4 x^T frags built from 8 coalesced global dwords each
// (RNE-packed in-register). Frag is B for Q/K and A for swapped V.
// qbuf [n][h][l][d] PRE-SCALED by log2e/16; kbuf [n][h][l][d] (8B stores).
// vbuf [n][c][2048] in the A-frag l-permuted layout (pos p=quad*8+j holds
// l = 32g + (j<4 ? 4*quad+j : 16+4*quad+j-4)), two 16B stores per lane.
__global__ __launch_bounds__(256) void qkv_proj(
    const float* __restrict__ x, const u16* __restrict__ Wq,
    const u16* __restrict__ Wk, const u16* __restrict__ Wv,
    u16* __restrict__ qbuf, u16* __restrict__ kbuf, u16* __restrict__ vbuf) {
  const int n = blockIdx.z;
  const int o0 = blockIdx.y * 64;
  const int l0 = blockIdx.x * 64;
  const int tid = threadIdx.x;
  const int w = tid >> 6, lane = tid & 63, quad = lane >> 4, l16 = lane & 15;
  const int ow = o0 + w * 16;
  const float SC = 0.09019327066650391f;   // log2(e)/16

  f4 accq[4], acck[4], accv[4];
#pragma unroll
  for (int lt = 0; lt < 4; ++lt) {
    accq[lt] = (f4){0.f, 0.f, 0.f, 0.f};
    acck[lt] = (f4){0.f, 0.f, 0.f, 0.f};
    accv[lt] = (f4){0.f, 0.f, 0.f, 0.f};
  }

  const u16* wqp = Wq + (ow + l16) * 256 + quad * 8;
  const u16* wkp = Wk + (ow + l16) * 256 + quad * 8;
  const u16* wvp = Wv + (ow + l16) * 256 + quad * 8;
  // x base for this lane: row c = quad*8 (+j), col l = l0 + l16 (+lt*16)
  const float* xb = x + ((size_t)(n * 256 + quad * 8)) * 2048 + l0 + l16;

#pragma unroll
  for (int s = 0; s < 8; ++s) {
    const int c0 = s * 32;
    bf8 a0 = *(const bf8*)(wqp + c0);
    bf8 a1 = *(const bf8*)(wkp + c0);
    bf8 a2 = *(const bf8*)(wvp + c0);
#pragma unroll
    for (int lt = 0; lt < 4; ++lt) {
      const float* xp = xb + (size_t)c0 * 2048 + lt * 16;
      float v0 = xp[0 * 2048], v1 = xp[1 * 2048], v2 = xp[2 * 2048], v3 = xp[3 * 2048];
      float v4 = xp[4 * 2048], v5 = xp[5 * 2048], v6 = xp[6 * 2048], v7 = xp[7 * 2048];
      bf8 b = mkbf8(pk2bf(v0, v1), pk2bf(v2, v3), pk2bf(v4, v5), pk2bf(v6, v7));
      accq[lt] = MFMA(a0, b, accq[lt]);
      acck[lt] = MFMA(a1, b, acck[lt]);
      accv[lt] = MFMA(b, a2, accv[lt]);   // swapped: C[l][o], o = ow + l16
    }
  }

  // ---- epilogue (identical to R14) ----
  const int hh = ow >> 5;                        // head index (const over r)
  const int dbase = (ow & 31) + quad * 4;        // d offset, 8B aligned
#pragma unroll
  for (int lt = 0; lt < 4; ++lt) {
    const int l = l0 + lt * 16 + l16;
    const size_t base = ((size_t)(n * 8 + hh) * 2048 + l) * 32 + dbase;
    u16x4 qv, kv;
#pragma unroll
    for (int r = 0; r < 4; ++r) {
      qv[r] = f2bf(accq[lt][r] * SC);
      kv[r] = f2bf(acck[lt][r]);
    }
    *(u16x4*)(qbuf + base) = qv;
    *(u16x4*)(kbuf + base) = kv;
  }
  // V: lane holds l = 32g+4quad+r (tile 2g) and 32g+16+4quad+r (tile 2g+1),
  // d-col o = ow + l16 -> exactly the permuted-A-frag 16B run.
#pragma unroll
  for (int g = 0; g < 2; ++g) {
    u16x8 vv;
#pragma unroll
    for (int r = 0; r < 4; ++r) {
      vv[r] = f2bf(accv[2 * g][r]);
      vv[4 + r] = f2bf(accv[2 * g + 1][r]);
    }
    *(u16x8*)(vbuf + ((size_t)(n * 256 + ow + l16)) * 2048 + l0 + g * 32 + quad * 8) = vv;
  }
}

// ---------------------------------------------------------------------------
// Kernel 2 (FROZEN from R14): attention, 4 waves/block, split-K: wave w covers
// k in [512w,512w+512) for the same 64 q; one LDS combine. Zero-LDS main loop:
// S^T = K*Q^T, lane-local exp2 + pktrunc packs -> PV B-frags, permuted-V 16B
// A-frags. No explicit prefetch (occupancy hides latency); scalar lsum.
// Grid (64 head, 32 qblk): linear = head + 64*qblk -> head h on XCD h%8.
__global__ __launch_bounds__(256) void attn(
    const u16* __restrict__ qbuf, const u16* __restrict__ kbuf,
    const u16* __restrict__ vbuf, u16* __restrict__ abuf) {
  __shared__ float Osh[3][64][37];              // waves 1..3 partials, pad 37
  const int head = blockIdx.x, qblk = blockIdx.y;
  const int n = head >> 3, h = head & 7;
  const int tid = threadIdx.x;
  const int w = tid >> 6, lane = tid & 63;
  const int quad = lane >> 4, l16 = lane & 15;
  const int q0 = qblk * 64;
  const int kc0 = w * 512;

  const u16* kb = kbuf + (size_t)head * 2048 * 32 + l16 * 32 + quad * 8;
  const u16* vb = vbuf + ((size_t)n * 256 + h * 32 + l16) * 2048 + quad * 8;

  bf8 aq[4];                                    // Q B-op frags (16x16x32)
#pragma unroll
  for (int qt = 0; qt < 4; ++qt)
    aq[qt] = *(const bf8*)(qbuf + ((size_t)head * 2048 + q0 + qt * 16 + l16) * 32 + quad * 8);

  f4 O[2][4];                                   // O^T accum [dt][qt]
  float lsum[4];
#pragma unroll
  for (int qt = 0; qt < 4; ++qt) {
    O[0][qt] = (f4){0.f, 0.f, 0.f, 0.f};
    O[1][qt] = (f4){0.f, 0.f, 0.f, 0.f};
    lsum[qt] = 0.f;
  }

  for (int kc = kc0; kc < kc0 + 512; kc += 64) {
    bf8 bk[4], vf[4];
#pragma unroll
    for (int kt = 0; kt < 4; ++kt) bk[kt] = *(const bf8*)(kb + (kc + kt * 16) * 32);
#pragma unroll
    for (int dt = 0; dt < 2; ++dt)
#pragma unroll
      for (int g = 0; g < 2; ++g)
        vf[dt * 2 + g] = *(const bf8*)(vb + dt * 16 * 2048 + kc + g * 32);

#pragma unroll
    for (int qt = 0; qt < 4; ++qt) {
      f4 z = (f4){0.f, 0.f, 0.f, 0.f};
      f4 s0 = MFMA(bk[0], aq[qt], z);           // S^T tiles (A=K, B=Q)
      f4 s1 = MFMA(bk[1], aq[qt], z);
      f4 s2 = MFMA(bk[2], aq[qt], z);
      f4 s3 = MFMA(bk[3], aq[qt], z);
      f4 e0, e1, e2, e3;
#pragma unroll
      for (int r = 0; r < 4; ++r) {
        e0[r] = exp2_fast(s0[r]);               // scale pre-folded into qbuf
        e1[r] = exp2_fast(s1[r]);
        e2[r] = exp2_fast(s2[r]);
        e3[r] = exp2_fast(s3[r]);
      }
      f4 t01 = e0 + e1, t23 = e2 + e3;
      f4 t = t01 + t23;
      lsum[qt] += (t[0] + t[1]) + (t[2] + t[3]);
      // B-frags: group 0 = tiles 0,1; group 1 = tiles 2,3 (k-permuted pi)
      bf8 B0 = mkbf8(pktrunc(e0[0], e0[1]), pktrunc(e0[2], e0[3]),
                     pktrunc(e1[0], e1[1]), pktrunc(e1[2], e1[3]));
      bf8 B1 = mkbf8(pktrunc(e2[0], e2[1]), pktrunc(e2[2], e2[3]),
                     pktrunc(e3[0], e3[1]), pktrunc(e3[2], e3[3]));
#pragma unroll
      for (int dt = 0; dt < 2; ++dt) {
        f4 o = O[dt][qt];
        o = MFMA(vf[dt * 2 + 0], B0, o);        // A = permuted V (direct 16B)
        o = MFMA(vf[dt * 2 + 1], B1, o);
        O[dt][qt] = o;
      }
    }
  }

  // per-qt: reduce lsum across the 4 quads holding this q's k-slices
#pragma unroll
  for (int qt = 0; qt < 4; ++qt) {
    float s = lsum[qt];
    s += __shfl_xor(s, 16);
    s += __shfl_xor(s, 32);
    lsum[qt] = s;
  }

  // ---- split-K combine: waves 1..3 park partials in LDS; wave 0 reduces ----
  if (w > 0) {
#pragma unroll
    for (int dt = 0; dt < 2; ++dt)
#pragma unroll
      for (int qt = 0; qt < 4; ++qt)
#pragma unroll
        for (int r = 0; r < 4; ++r)
          Osh[w - 1][lane][dt * 16 + qt * 4 + r] = O[dt][qt][r];
#pragma unroll
    for (int qt = 0; qt < 4; ++qt)
      Osh[w - 1][lane][32 + qt] = lsum[qt];
  }
  __syncthreads();
  if (w == 0) {
#pragma unroll
    for (int p = 0; p < 3; ++p) {
#pragma unroll
      for (int dt = 0; dt < 2; ++dt)
#pragma unroll
        for (int qt = 0; qt < 4; ++qt)
#pragma unroll
          for (int r = 0; r < 4; ++r)
            O[dt][qt][r] += Osh[p][lane][dt * 16 + qt * 4 + r];
#pragma unroll
      for (int qt = 0; qt < 4; ++qt)
        lsum[qt] += Osh[p][lane][32 + qt];
    }
#pragma unroll
    for (int qt = 0; qt < 4; ++qt) {
      const float inv = 1.0f / lsum[qt];        // q = l16
      const int q = q0 + qt * 16 + l16;
#pragma unroll
      for (int dt = 0; dt < 2; ++dt) {
        u16x4 ov;
#pragma unroll
        for (int r = 0; r < 4; ++r) ov[r] = f2bf(O[dt][qt][r] * inv);
        *(u16x4*)(abuf + ((size_t)n * 2048 + q) * 256 + h * 32 + dt * 16 + quad * 4) = ov;
      }
    }
  }
}

// ---------------------------------------------------------------------------
// Kernel 3 (FROZEN from R14): out = Wo @ attn_out + bo (fp32 output).
// attn_out stored [n][l][c] = B^T form -> 16B contiguous B-frag loads;
// next-iter prefetch on both A & B; bf16 Wo/bo from convert.
__global__ __launch_bounds__(256) void out_proj(
    const u16* __restrict__ abuf, const u16* __restrict__ Wo,
    const u16* __restrict__ bo, float* __restrict__ out) {
  const int n = blockIdx.z;
  const int o0 = blockIdx.y * 64;
  const int l0 = blockIdx.x * 64;
  const int tid = threadIdx.x;
  const int w = tid >> 6, lane = tid & 63, quad = lane >> 4, l16 = lane & 15;
  const int ow = o0 + w * 16;

  const u16* wp = Wo + (ow + l16) * 256 + quad * 8;
  const u16* ab = abuf + ((size_t)n * 2048 + l0 + l16) * 256 + quad * 8;

  f4 acc[4];
#pragma unroll
  for (int lt = 0; lt < 4; ++lt) acc[lt] = (f4){0.f, 0.f, 0.f, 0.f};

  bf8 a = *(const bf8*)wp;
  bf8 b[4];
#pragma unroll
  for (int lt = 0; lt < 4; ++lt) b[lt] = *(const bf8*)(ab + lt * 16 * 256);

  for (int c0 = 0; c0 < 256; c0 += 32) {
    const int cn = (c0 < 224) ? c0 + 32 : 0;
    bf8 na = *(const bf8*)(wp + cn);
    bf8 nb[4];
#pragma unroll
    for (int lt = 0; lt < 4; ++lt)
      nb[lt] = *(const bf8*)(ab + lt * 16 * 256 + cn);
#pragma unroll
    for (int lt = 0; lt < 4; ++lt) acc[lt] = MFMA(a, b[lt], acc[lt]);
    a = na;
#pragma unroll
    for (int lt = 0; lt < 4; ++lt) b[lt] = nb[lt];
  }
#pragma unroll
  for (int r = 0; r < 4; ++r) {
    const int o = ow + quad * 4 + r;
    const float bias = bf2f(bo[o]);
#pragma unroll
    for (int lt = 0; lt < 4; ++lt) {
      out[((size_t)n * 256 + o) * 2048 + l0 + lt * 16 + l16] = acc[lt][r] + bias;
    }
  }
}

// ---------------------------------------------------------------------------
extern "C" void kernel_launch(void* const* d_in, const int* in_sizes, int n_in,
                              void* d_out, int out_size, void* d_ws, size_t ws_size,
                              hipStream_t stream) {
  const float* x  = (const float*)d_in[0];
  const float* Wq = (const float*)d_in[1];
  const float* Wk = (const float*)d_in[2];
  const float* Wv = (const float*)d_in[3];
  const float* Wo = (const float*)d_in[4];
  const float* bo = (const float*)d_in[5];
  float* out = (float*)d_out;

  u16* ws = (u16*)d_ws;
  u16* qbuf = ws;                      // [8][8][2048][32] bf16 = 8 MB (pre-scaled)
  u16* kbuf = qbuf + 4194304;          // 8 MB
  u16* vbuf = kbuf + 4194304;          // [8][256][2048]   = 8 MB (A-frag permuted)
  u16* abuf = vbuf + 4194304;          // [8][2048][256]   = 8 MB
  u16* Wqb  = abuf + 4194304;          // 128 KB each
  u16* Wkb  = Wqb + 65536;
  u16* Wvb  = Wkb + 65536;
  u16* Wob  = Wvb + 65536;
  u16* bob  = Wob + 65536;             // 512 B

  convert_weights<<<dim3(256), 256, 0, stream>>>(Wq, Wk, Wv, Wo, bo,
                                                 Wqb, Wkb, Wvb, Wob, bob);
  qkv_proj<<<dim3(32, 4, 8), 256, 0, stream>>>(x, Wqb, Wkb, Wvb,
                                               qbuf, kbuf, vbuf);
  attn<<<dim3(64, 32), 256, 0, stream>>>(qbuf, kbuf, vbuf, abuf);
  out_proj<<<dim3(32, 4, 8), 256, 0, stream>>>(abuf, Wob, bob, out);
}

// Round 18
// 165.036 us; speedup vs baseline: 1.0984x; 1.0442x over previous
//
#include <hip/hip_runtime.h>

// MultiHeadAttention: N=8, C=256, L=2048, H=8, D=32. softmax scale = C^-0.5 = 1/16.
// Inputs fp32, output fp32. Internal bf16 MFMA, fp32 accumulate.
// R18 = R14 verbatim (best: 166.3us). Cooperative fusion (R17) is unsupported
// under the harness's graph capture (kernel never ran); all other projection /
// attn restructurings measured worse. Structure:
//  - convert_weights: fp32 -> bf16 weight copies (one dispatch; twice-confirmed
//    better than inline per-block conversion).
//  - qkv_proj: double-buffered LDS x-staging, operand-swapped V (two 16B
//    stores into A-frag-permuted vbuf), packed 8B q/k stores, q pre-scaled.
//  - attn: 4-wave split-K (512 k/wave), zero-LDS main loop (S^T = K*Q^T,
//    lane-local exp2+pack into PV B-frags, permuted-V 16B A-frags), no
//    explicit prefetch (occupancy > prefetch at VGPR 76), one LDS combine.
//  - out_proj: direct-global B^T GEMM with prefetch-1.

typedef __bf16 bf8 __attribute__((ext_vector_type(8)));
typedef float f4 __attribute__((ext_vector_type(4)));
typedef float f32x4 __attribute__((ext_vector_type(4)));
typedef unsigned short u16;
typedef unsigned int u32;
typedef u16 u16x4 __attribute__((ext_vector_type(4)));
typedef u16 u16x8 __attribute__((ext_vector_type(8)));

__device__ __forceinline__ u16 f2bf(float f) {
  __bf16 h = (__bf16)f;                 // v_cvt (RNE)
  return __builtin_bit_cast(u16, h);
}
__device__ __forceinline__ float bf2f(u16 b) {
  union { u32 u; float f; } v; v.u = ((u32)b) << 16;
  return v.f;
}
__device__ __forceinline__ u32 pk2bf(float a, float b) {  // low=a, high=b (RNE)
  return ((u32)f2bf(b) << 16) | (u32)f2bf(a);
}
// truncating pack: low16 = hi16(a), high16 = hi16(b); 1 v_perm_b32
__device__ __forceinline__ u32 pktrunc(float a, float b) {
  return __builtin_amdgcn_perm(__builtin_bit_cast(u32, b),
                               __builtin_bit_cast(u32, a), 0x07060302u);
}
__device__ __forceinline__ float exp2_fast(float x) {
  return __builtin_amdgcn_exp2f(x);     // v_exp_f32
}

#define MFMA(a, b, c) __builtin_amdgcn_mfma_f32_16x16x32_bf16((a), (b), (c), 0, 0, 0)

union bf8u { u32 u[4]; bf8 v; };
__device__ __forceinline__ bf8 mkbf8(u32 a, u32 b, u32 c, u32 d) {
  bf8u t; t.u[0] = a; t.u[1] = b; t.u[2] = c; t.u[3] = d; return t.v;
}

// ---------------------------------------------------------------------------
// Kernel 0: convert Wq/Wk/Wv/Wo/bo fp32 -> bf16 ws copies.
__global__ __launch_bounds__(256) void convert_weights(
    const float* __restrict__ Wq, const float* __restrict__ Wk,
    const float* __restrict__ Wv, const float* __restrict__ Wo,
    const float* __restrict__ bo,
    u16* __restrict__ Wqb, u16* __restrict__ Wkb, u16* __restrict__ Wvb,
    u16* __restrict__ Wob, u16* __restrict__ bob) {
  const int tid = threadIdx.x;
  const int seg = blockIdx.x >> 6;
  const int blk = blockIdx.x & 63;
  const float* s; u16* d;
  if (seg == 0)      { s = Wq; d = Wqb; }
  else if (seg == 1) { s = Wk; d = Wkb; }
  else if (seg == 2) { s = Wv; d = Wvb; }
  else               { s = Wo; d = Wob; }
  const int base = blk * 1024 + tid * 4;
  f32x4 v = *(const f32x4*)(s + base);
  u16x4 o;
#pragma unroll
  for (int i = 0; i < 4; ++i) o[i] = f2bf(v[i]);
  *(u16x4*)(d + base) = o;
  if (blockIdx.x == 0 && tid < 64) {
    const int bb = tid * 4;
    f32x4 bv = *(const f32x4*)(bo + bb);
    u16x4 ob;
#pragma unroll
    for (int i = 0; i < 4; ++i) ob[i] = f2bf(bv[i]);
    *(u16x4*)(bob + bb) = ob;
  }
}

// ---------------------------------------------------------------------------
// Kernel 1: Q/K/V projections, double-buffered x staging (fp32 in), bf16 W.
// qbuf [n][h][l][d] PRE-SCALED by log2e/16; kbuf [n][h][l][d] (packed 8B st).
// V computed operand-swapped (C[l][o]) -> vbuf [n][c][2048] in the A-frag
// l-permuted layout (pos p=quad*8+j holds l=32g + (j<4?4q+j:16+4q+j-4)),
// written as two coalesced 16B stores per lane.
__global__ __launch_bounds__(256) void qkv_proj(
    const float* __restrict__ x, const u16* __restrict__ Wq,
    const u16* __restrict__ Wk, const u16* __restrict__ Wv,
    u16* __restrict__ qbuf, u16* __restrict__ kbuf, u16* __restrict__ vbuf) {
  __shared__ __align__(16) u16 xt[2][64 * 40];   // x^T tile [64 l][32 c], pad 40
  const int n = blockIdx.z;
  const int o0 = blockIdx.y * 64;
  const int l0 = blockIdx.x * 64;
  const int tid = threadIdx.x;
  const int w = tid >> 6, lane = tid & 63, quad = lane >> 4, l16 = lane & 15;
  const int ow = o0 + w * 16;
  const float SC = 0.09019327066650391f;   // log2(e)/16

  f4 accq[4], acck[4], accv[4];
#pragma unroll
  for (int lt = 0; lt < 4; ++lt) {
    accq[lt] = (f4){0.f, 0.f, 0.f, 0.f};
    acck[lt] = (f4){0.f, 0.f, 0.f, 0.f};
    accv[lt] = (f4){0.f, 0.f, 0.f, 0.f};
  }

  const int cp = tid >> 4;            // c-pair 0..15 -> c = 2cp, 2cp+1
  const int lq = (tid & 15) * 4;      // 4 l's

  auto stage = [&](int c0, int buf) {
    const float* xp = x + (n * 256 + c0 + 2 * cp) * 2048 + l0 + lq;
    f32x4 r0 = *(const f32x4*)xp;
    f32x4 r1 = *(const f32x4*)(xp + 2048);
#pragma unroll
    for (int i = 0; i < 4; ++i)
      *(u32*)&xt[buf][(lq + i) * 40 + 2 * cp] = pk2bf(r0[i], r1[i]);
  };

  stage(0, 0);
  for (int s = 0; s < 8; ++s) {
    __syncthreads();
    if (s < 7) stage((s + 1) * 32, (s + 1) & 1);
    const int c0 = s * 32;
    bf8 a0 = *(const bf8*)(Wq + (ow + l16) * 256 + c0 + quad * 8);
    bf8 a1 = *(const bf8*)(Wk + (ow + l16) * 256 + c0 + quad * 8);
    bf8 a2 = *(const bf8*)(Wv + (ow + l16) * 256 + c0 + quad * 8);
    const u16* xb = xt[s & 1];
#pragma unroll
    for (int lt = 0; lt < 4; ++lt) {
      bf8 b = *(const bf8*)&xb[(lt * 16 + l16) * 40 + quad * 8];
      accq[lt] = MFMA(a0, b, accq[lt]);
      acck[lt] = MFMA(a1, b, acck[lt]);
      accv[lt] = MFMA(b, a2, accv[lt]);   // swapped: C[l][o], o = ow + l16
    }
  }

  // ---- epilogue ----
  const int hh = ow >> 5;                        // head index (const over r)
  const int dbase = (ow & 31) + quad * 4;        // d offset, 8B aligned
#pragma unroll
  for (int lt = 0; lt < 4; ++lt) {
    const int l = l0 + lt * 16 + l16;
    const size_t base = ((size_t)(n * 8 + hh) * 2048 + l) * 32 + dbase;
    u16x4 qv, kv;
#pragma unroll
    for (int r = 0; r < 4; ++r) {
      qv[r] = f2bf(accq[lt][r] * SC);
      kv[r] = f2bf(acck[lt][r]);
    }
    *(u16x4*)(qbuf + base) = qv;
    *(u16x4*)(kbuf + base) = kv;
  }
  // V: lane holds l = 32g+4quad+r (tile 2g) and 32g+16+4quad+r (tile 2g+1),
  // d-col o = ow + l16 -> exactly the permuted-A-frag 16B run.
#pragma unroll
  for (int g = 0; g < 2; ++g) {
    u16x8 vv;
#pragma unroll
    for (int r = 0; r < 4; ++r) {
      vv[r] = f2bf(accv[2 * g][r]);
      vv[4 + r] = f2bf(accv[2 * g + 1][r]);
    }
    *(u16x8*)(vbuf + ((size_t)(n * 256 + ow + l16)) * 2048 + l0 + g * 32 + quad * 8) = vv;
  }
}

// ---------------------------------------------------------------------------
// Kernel 2: attention, 4 waves/block, split-K: wave w covers k in
// [512w,512w+512) for the same 64 q; one LDS combine. Zero-LDS main loop:
// S^T = K*Q^T, lane-local exp2 + pktrunc packs -> PV B-frags, permuted-V 16B
// A-frags. No explicit prefetch (occupancy hides latency); scalar lsum.
// Grid (64 head, 32 qblk): linear = head + 64*qblk -> head h on XCD h%8.
__global__ __launch_bounds__(256) void attn(
    const u16* __restrict__ qbuf, const u16* __restrict__ kbuf,
    const u16* __restrict__ vbuf, u16* __restrict__ abuf) {
  __shared__ float Osh[3][64][37];              // waves 1..3 partials, pad 37
  const int head = blockIdx.x, qblk = blockIdx.y;
  const int n = head >> 3, h = head & 7;
  const int tid = threadIdx.x;
  const int w = tid >> 6, lane = tid & 63;
  const int quad = lane >> 4, l16 = lane & 15;
  const int q0 = qblk * 64;
  const int kc0 = w * 512;

  const u16* kb = kbuf + (size_t)head * 2048 * 32 + l16 * 32 + quad * 8;
  const u16* vb = vbuf + ((size_t)n * 256 + h * 32 + l16) * 2048 + quad * 8;

  bf8 aq[4];                                    // Q B-op frags (16x16x32)
#pragma unroll
  for (int qt = 0; qt < 4; ++qt)
    aq[qt] = *(const bf8*)(qbuf + ((size_t)head * 2048 + q0 + qt * 16 + l16) * 32 + quad * 8);

  f4 O[2][4];                                   // O^T accum [dt][qt]
  float lsum[4];
#pragma unroll
  for (int qt = 0; qt < 4; ++qt) {
    O[0][qt] = (f4){0.f, 0.f, 0.f, 0.f};
    O[1][qt] = (f4){0.f, 0.f, 0.f, 0.f};
    lsum[qt] = 0.f;
  }

  for (int kc = kc0; kc < kc0 + 512; kc += 64) {
    bf8 bk[4], vf[4];
#pragma unroll
    for (int kt = 0; kt < 4; ++kt) bk[kt] = *(const bf8*)(kb + (kc + kt * 16) * 32);
#pragma unroll
    for (int dt = 0; dt < 2; ++dt)
#pragma unroll
      for (int g = 0; g < 2; ++g)
        vf[dt * 2 + g] = *(const bf8*)(vb + dt * 16 * 2048 + kc + g * 32);

#pragma unroll
    for (int qt = 0; qt < 4; ++qt) {
      f4 z = (f4){0.f, 0.f, 0.f, 0.f};
      f4 s0 = MFMA(bk[0], aq[qt], z);           // S^T tiles (A=K, B=Q)
      f4 s1 = MFMA(bk[1], aq[qt], z);
      f4 s2 = MFMA(bk[2], aq[qt], z);
      f4 s3 = MFMA(bk[3], aq[qt], z);
      f4 e0, e1, e2, e3;
#pragma unroll
      for (int r = 0; r < 4; ++r) {
        e0[r] = exp2_fast(s0[r]);               // scale pre-folded into qbuf
        e1[r] = exp2_fast(s1[r]);
        e2[r] = exp2_fast(s2[r]);
        e3[r] = exp2_fast(s3[r]);
      }
      f4 t01 = e0 + e1, t23 = e2 + e3;
      f4 t = t01 + t23;
      lsum[qt] += (t[0] + t[1]) + (t[2] + t[3]);
      // B-frags: group 0 = tiles 0,1; group 1 = tiles 2,3 (k-permuted pi)
      bf8 B0 = mkbf8(pktrunc(e0[0], e0[1]), pktrunc(e0[2], e0[3]),
                     pktrunc(e1[0], e1[1]), pktrunc(e1[2], e1[3]));
      bf8 B1 = mkbf8(pktrunc(e2[0], e2[1]), pktrunc(e2[2], e2[3]),
                     pktrunc(e3[0], e3[1]), pktrunc(e3[2], e3[3]));
#pragma unroll
      for (int dt = 0; dt < 2; ++dt) {
        f4 o = O[dt][qt];
        o = MFMA(vf[dt * 2 + 0], B0, o);        // A = permuted V (direct 16B)
        o = MFMA(vf[dt * 2 + 1], B1, o);
        O[dt][qt] = o;
      }
    }
  }

  // per-qt: reduce lsum across the 4 quads holding this q's k-slices
#pragma unroll
  for (int qt = 0; qt < 4; ++qt) {
    float s = lsum[qt];
    s += __shfl_xor(s, 16);
    s += __shfl_xor(s, 32);
    lsum[qt] = s;
  }

  // ---- split-K combine: waves 1..3 park partials in LDS; wave 0 reduces ----
  if (w > 0) {
#pragma unroll
    for (int dt = 0; dt < 2; ++dt)
#pragma unroll
      for (int qt = 0; qt < 4; ++qt)
#pragma unroll
        for (int r = 0; r < 4; ++r)
          Osh[w - 1][lane][dt * 16 + qt * 4 + r] = O[dt][qt][r];
#pragma unroll
    for (int qt = 0; qt < 4; ++qt)
      Osh[w - 1][lane][32 + qt] = lsum[qt];
  }
  __syncthreads();
  if (w == 0) {
#pragma unroll
    for (int p = 0; p < 3; ++p) {
#pragma unroll
      for (int dt = 0; dt < 2; ++dt)
#pragma unroll
        for (int qt = 0; qt < 4; ++qt)
#pragma unroll
          for (int r = 0; r < 4; ++r)
            O[dt][qt][r] += Osh[p][lane][dt * 16 + qt * 4 + r];
#pragma unroll
      for (int qt = 0; qt < 4; ++qt)
        lsum[qt] += Osh[p][lane][32 + qt];
    }
#pragma unroll
    for (int qt = 0; qt < 4; ++qt) {
      const float inv = 1.0f / lsum[qt];        // q = l16
      const int q = q0 + qt * 16 + l16;
#pragma unroll
      for (int dt = 0; dt < 2; ++dt) {
        u16x4 ov;
#pragma unroll
        for (int r = 0; r < 4; ++r) ov[r] = f2bf(O[dt][qt][r] * inv);
        *(u16x4*)(abuf + ((size_t)n * 2048 + q) * 256 + h * 32 + dt * 16 + quad * 4) = ov;
      }
    }
  }
}

// ---------------------------------------------------------------------------
// Kernel 3: out = Wo @ attn_out + bo (fp32 output).  attn_out stored [n][l][c]
// = B^T form -> 16B contiguous B-frag loads; next-iter prefetch on both A & B.
__global__ __launch_bounds__(256) void out_proj(
    const u16* __restrict__ abuf, const u16* __restrict__ Wo,
    const u16* __restrict__ bo, float* __restrict__ out) {
  const int n = blockIdx.z;
  const int o0 = blockIdx.y * 64;
  const int l0 = blockIdx.x * 64;
  const int tid = threadIdx.x;
  const int w = tid >> 6, lane = tid & 63, quad = lane >> 4, l16 = lane & 15;
  const int ow = o0 + w * 16;

  const u16* wp = Wo + (ow + l16) * 256 + quad * 8;
  const u16* ab = abuf + ((size_t)n * 2048 + l0 + l16) * 256 + quad * 8;

  f4 acc[4];
#pragma unroll
  for (int lt = 0; lt < 4; ++lt) acc[lt] = (f4){0.f, 0.f, 0.f, 0.f};

  bf8 a = *(const bf8*)wp;
  bf8 b[4];
#pragma unroll
  for (int lt = 0; lt < 4; ++lt) b[lt] = *(const bf8*)(ab + lt * 16 * 256);

  for (int c0 = 0; c0 < 256; c0 += 32) {
    const int cn = (c0 < 224) ? c0 + 32 : 0;
    bf8 na = *(const bf8*)(wp + cn);
    bf8 nb[4];
#pragma unroll
    for (int lt = 0; lt < 4; ++lt)
      nb[lt] = *(const bf8*)(ab + lt * 16 * 256 + cn);
#pragma unroll
    for (int lt = 0; lt < 4; ++lt) acc[lt] = MFMA(a, b[lt], acc[lt]);
    a = na;
#pragma unroll
    for (int lt = 0; lt < 4; ++lt) b[lt] = nb[lt];
  }
#pragma unroll
  for (int r = 0; r < 4; ++r) {
    const int o = ow + quad * 4 + r;
    const float bias = bf2f(bo[o]);
#pragma unroll
    for (int lt = 0; lt < 4; ++lt) {
      out[((size_t)n * 256 + o) * 2048 + l0 + lt * 16 + l16] = acc[lt][r] + bias;
    }
  }
}

// ---------------------------------------------------------------------------
extern "C" void kernel_launch(void* const* d_in, const int* in_sizes, int n_in,
                              void* d_out, int out_size, void* d_ws, size_t ws_size,
                              hipStream_t stream) {
  const float* x  = (const float*)d_in[0];
  const float* Wq = (const float*)d_in[1];
  const float* Wk = (const float*)d_in[2];
  const float* Wv = (const float*)d_in[3];
  const float* Wo = (const float*)d_in[4];
  const float* bo = (const float*)d_in[5];
  float* out = (float*)d_out;

  u16* ws = (u16*)d_ws;
  u16* qbuf = ws;                      // [8][8][2048][32] bf16 = 8 MB (pre-scaled)
  u16* kbuf = qbuf + 4194304;          // 8 MB
  u16* vbuf = kbuf + 4194304;          // [8][256][2048]   = 8 MB (A-frag permuted)
  u16* abuf = vbuf + 4194304;          // [8][2048][256]   = 8 MB
  u16* Wqb  = abuf + 4194304;          // 128 KB each
  u16* Wkb  = Wqb + 65536;
  u16* Wvb  = Wkb + 65536;
  u16* Wob  = Wvb + 65536;
  u16* bob  = Wob + 65536;             // 512 B

  convert_weights<<<dim3(256), 256, 0, stream>>>(Wq, Wk, Wv, Wo, bo,
                                                 Wqb, Wkb, Wvb, Wob, bob);
  qkv_proj<<<dim3(32, 4, 8), 256, 0, stream>>>(x, Wqb, Wkb, Wvb,
                                               qbuf, kbuf, vbuf);
  attn<<<dim3(64, 32), 256, 0, stream>>>(qbuf, kbuf, vbuf, abuf);
  out_proj<<<dim3(32, 4, 8), 256, 0, stream>>>(abuf, Wob, bob, out);
}